// Round 2
// baseline (2333.632 us; speedup 1.0000x reference)
//
#include <hip/hip_runtime.h>
#include <stdint.h>

// SNN audio classifier. One block per sample, T=100 loop in-kernel.
// Round 2: register-resident weights/membranes, bit-packed spikes for conv2
// (ballot pack + register bit-extract), prefetched x, 3 barriers/step.

#define NB 512
#define NT 100
#define LIN 686
#define C1 16
#define O1 136
#define P1 68
#define K1 13
#define S1 5
#define C2 32
#define O2 22
#define K2 7
#define S2 3
#define F1 704   // C2*O2
#define H1 32
#define SP 73    // spool row stride (floats); cols 0..69 used, 70..72 always 0

__global__ __launch_bounds__(256, 2) void snn_all(
    const float* __restrict__ x,
    const float* __restrict__ w1, const float* __restrict__ b1,
    const float* __restrict__ w2, const float* __restrict__ b2,
    const float* __restrict__ wf1, const float* __restrict__ bf1,
    const float* __restrict__ wf2, const float* __restrict__ bf2,
    float* __restrict__ out)
{
    __shared__ __align__(16) float sx[LIN + 2];     // padded conv1 input
    __shared__ float spool[C1 * SP];                // pooled spikes (padded rows)
    __shared__ __align__(16) float sspk2[F1];       // flattened spk2 (c-major)
    __shared__ float sspk3[H1];

    const int tid  = threadIdx.x;
    const int b    = blockIdx.x;
    const int lane = tid & 63;
    const int wv   = tid >> 6;        // wave id 0..3

    // ---------- phase A setup: conv1. thread = (channel ca, pool-group pg) ----------
    const int ca = tid & 15;
    const int pg = tid >> 4;          // 0..15
    float wA[K1];
    #pragma unroll
    for (int k = 0; k < K1; ++k) wA[k] = w1[ca * K1 + k];
    const float bA = b1[ca];
    float m1[5][2];                   // conv1 membranes (register-resident)
    #pragma unroll
    for (int j = 0; j < 5; ++j) { m1[j][0] = 0.f; m1[j][1] = 0.f; }

    // ---------- phase B setup: conv2. lane = (channel cb, i-half ih) ----------
    const int cb = tid & 31;
    const int ih = (tid >> 5) & 1;
    float wB[8][K2];                  // 56 weights in registers
    #pragma unroll
    for (int ii = 0; ii < 8; ++ii)
        #pragma unroll
        for (int k = 0; k < K2; ++k)
            wB[ii][k] = w2[cb * (C1 * K2) + (ih * 8 + ii) * K2 + k];
    const float bB = b2[cb];
    float m2[6];                      // conv2 membranes for this wave's outputs
    #pragma unroll
    for (int j = 0; j < 6; ++j) m2[j] = 0.f;

    // ---------- phase C setup: fc1. thread = (row jc, slice sub) ----------
    const int jc = tid >> 3, sub = tid & 7;
    const float bC = bf1[jc];
    float m3 = 0.f;

    // ---------- phase D setup: fc2, wave 0 only ----------
    float wD = 0.f, bD = 0.f;
    if (tid < 64) {
        wD = wf2[(tid >> 5) * H1 + (tid & 31)];
        if ((tid & 31) == 0) bD = bf2[tid >> 5];
    }
    float m4 = 0.f, cnt = 0.f;

    // ---------- init LDS ----------
    for (int i = tid; i < C1 * SP; i += 256) spool[i] = 0.f;  // pads stay 0 forever
    const float* xb = x + (size_t)b * NT * LIN;
    if (tid == 0) { sx[0] = 0.f; sx[LIN + 1] = 0.f; }
    sx[1 + tid]       = xb[tid];
    sx[1 + tid + 256] = xb[tid + 256];
    if (tid < LIN - 512) sx[1 + tid + 512] = xb[tid + 512];
    __syncthreads();

    for (int t = 0; t < NT; ++t) {
        // ============ phase A: conv1 (k13,s5,p1) + LIF1 + maxpool2 ============
        #pragma unroll
        for (int j = 0; j < 5; ++j) {
            int p = (j == 4) ? (64 + pg) : (pg + 16 * j);
            bool valid = (j < 4) || (pg < 4);
            if (valid) {
                float xr[18];
                #pragma unroll
                for (int e = 0; e < 9; ++e) {
                    float2 v = *reinterpret_cast<const float2*>(&sx[10 * p + 2 * e]);
                    xr[2 * e] = v.x; xr[2 * e + 1] = v.y;
                }
                float a0 = 0.f, a1 = 0.f;
                #pragma unroll
                for (int k = 0; k < K1; ++k) {
                    a0 += wA[k] * xr[k];
                    a1 += wA[k] * xr[k + S1];
                }
                float m0 = m1[j][0], mm = m1[j][1];
                float r0 = (m0 > 1.f) ? 1.f : 0.f;
                float r1 = (mm > 1.f) ? 1.f : 0.f;
                m0 = 0.9f * m0 + (a0 + bA) - r0;
                mm = 0.9f * mm + (a1 + bA) - r1;
                m1[j][0] = m0; m1[j][1] = mm;
                spool[ca * SP + 1 + p] = (m0 > 1.f || mm > 1.f) ? 1.f : 0.f;
            }
        }
        __syncthreads();   // bar1: spool ready

        // ============ prefetch x(t+1) into registers (hidden under B) ============
        float xp0 = 0.f, xp1 = 0.f, xp2 = 0.f;
        if (t + 1 < NT) {
            const float* xt = xb + (size_t)(t + 1) * LIN;
            xp0 = xt[tid];
            xp1 = xt[tid + 256];
            if (tid < LIN - 512) xp2 = xt[tid + 512];
        }

        // ============ phase B: pack pool bits (ballot), conv2 + LIF2 ============
        uint32_t rw0[8], rw1[8], rw2[8];   // this lane's 8 rows, 72 bits each
        #pragma unroll
        for (int ii = 0; ii < 8; ++ii) {
            float vA0 = spool[ii * SP + lane];
            float vA1 = spool[ii * SP + 64 + (lane & 7)];
            float vB0 = spool[(ii + 8) * SP + lane];
            float vB1 = spool[(ii + 8) * SP + 64 + (lane & 7)];
            uint64_t loA = __ballot(vA0 > 0.5f);
            uint32_t hiA = (uint32_t)__ballot(vA1 > 0.5f) & 0xffu;
            uint64_t loB = __ballot(vB0 > 0.5f);
            uint32_t hiB = (uint32_t)__ballot(vB1 > 0.5f) & 0xffu;
            rw0[ii] = ih ? (uint32_t)loB         : (uint32_t)loA;
            rw1[ii] = ih ? (uint32_t)(loB >> 32) : (uint32_t)(loA >> 32);
            rw2[ii] = ih ? hiB                   : hiA;
        }

        // write x(t+1) into sx (no reader until next phase A; bar2+bar3 separate)
        if (t + 1 < NT) {
            sx[1 + tid]       = xp0;
            sx[1 + tid + 256] = xp1;
            if (tid < LIN - 512) sx[1 + tid + 512] = xp2;
        }

        // wave wv handles outputs o = wv, wv+4, ... (uniform per wave)
        #pragma unroll
        for (int jj = 0; jj < 6; ++jj) {
            int o = 4 * jj + wv;
            if (o < O2) {
                uint32_t sh = 3 * (uint32_t)o;
                float acc0 = 0.f, acc1 = 0.f;
                #pragma unroll
                for (int ii = 0; ii < 8; ++ii) {
                    uint32_t lo_w = (sh < 32) ? rw0[ii] : rw1[ii];
                    uint32_t hi_w = (sh < 32) ? rw1[ii] : rw2[ii];
                    uint32_t win = (uint32_t)(((((uint64_t)hi_w) << 32) | lo_w) >> (sh & 31u));
                    float s = 0.f;
                    #pragma unroll
                    for (int k = 0; k < K2; ++k)
                        s += wB[ii][k] * (float)((win >> k) & 1u);
                    if (ii & 1) acc1 += s; else acc0 += s;
                }
                float acc = acc0 + acc1;
                acc += __shfl_xor(acc, 32);     // sum the two i-halves
                float m = m2[jj];
                float r = (m > 1.f) ? 1.f : 0.f;
                m = 0.9f * m + (acc + bB) - r;
                m2[jj] = m;
                if (!(tid & 32)) sspk2[cb * O2 + o] = (m > 1.f) ? 1.f : 0.f;
            }
        }
        __syncthreads();   // bar2: sspk2 ready

        // ============ phase C: fc1 (704->32) + LIF3 ============
        {
            const float4* wr = reinterpret_cast<const float4*>(wf1 + jc * F1 + sub * 88);
            const float4* sp = reinterpret_cast<const float4*>(&sspk2[sub * 88]);
            float a0 = 0.f, a1 = 0.f, a2 = 0.f, a3 = 0.f;
            #pragma unroll
            for (int i = 0; i < 22; ++i) {
                float4 w = wr[i]; float4 s = sp[i];
                a0 += w.x * s.x; a1 += w.y * s.y; a2 += w.z * s.z; a3 += w.w * s.w;
            }
            float acc = (a0 + a1) + (a2 + a3);
            acc += __shfl_down(acc, 4, 8);
            acc += __shfl_down(acc, 2, 8);
            acc += __shfl_down(acc, 1, 8);
            if (sub == 0) {
                float r = (m3 > 1.f) ? 1.f : 0.f;
                m3 = 0.9f * m3 + (acc + bC) - r;
                sspk3[jc] = (m3 > 1.f) ? 1.f : 0.f;
            }
        }
        __syncthreads();   // bar3: sspk3 ready

        // ============ phase D: fc2 (32->2) + LIF4 + spike count (wave 0) ============
        if (tid < 64) {
            float v = sspk3[tid & 31] * wD;
            v += __shfl_xor(v, 16, 32);
            v += __shfl_xor(v, 8, 32);
            v += __shfl_xor(v, 4, 32);
            v += __shfl_xor(v, 2, 32);
            v += __shfl_xor(v, 1, 32);
            if ((tid & 31) == 0) {
                float r = (m4 > 1.f) ? 1.f : 0.f;
                m4 = 0.9f * m4 + (v + bD) - r;
                if (m4 > 1.f) cnt += 1.f;
            }
        }
        // no barrier needed: D reads only sspk3; next writer of sspk3 is C(t+1),
        // which lies behind bar1(t+1)+bar2(t+1), both of which wave 0 must reach.
    }

    if (tid == 0)  out[b * 2 + 0] = cnt;
    if (tid == 32) out[b * 2 + 1] = cnt;
}

extern "C" void kernel_launch(void* const* d_in, const int* in_sizes, int n_in,
                              void* d_out, int out_size, void* d_ws, size_t ws_size,
                              hipStream_t stream) {
    const float* x   = (const float*)d_in[0];
    const float* w1  = (const float*)d_in[1];
    const float* b1  = (const float*)d_in[2];
    const float* w2  = (const float*)d_in[3];
    const float* b2  = (const float*)d_in[4];
    const float* wf1 = (const float*)d_in[5];
    const float* bf1 = (const float*)d_in[6];
    const float* wf2 = (const float*)d_in[7];
    const float* bf2 = (const float*)d_in[8];
    float* out = (float*)d_out;

    snn_all<<<NB, 256, 0, stream>>>(x, w1, b1, w2, b2, wf1, bf1, wf2, bf2, out);
}

// Round 3
// 544.093 us; speedup vs baseline: 4.2890x; 4.2890x over previous
//
#include <hip/hip_runtime.h>
#include <stdint.h>

// SNN audio classifier. 256 blocks x 512 threads; each block = 2 independent
// samples (half h = tid>>8). T=100 loop in-kernel. Membranes in registers,
// conv2 on ballot-bit-packed spikes, wf1 reordered into LDS once.

#define NB 512
#define NT 100
#define LIN 686
#define SP 73    // spool row stride; col0 + cols 69..72 are permanent zero pads

__device__ __forceinline__ float dpp_add8(float x) {
    int t;
    t = __builtin_amdgcn_mov_dpp(__float_as_int(x), 0x141, 0xf, 0xf, true); // row_half_mirror (l -> 7-l in 8)
    x += __int_as_float(t);
    t = __builtin_amdgcn_mov_dpp(__float_as_int(x), 0x1B, 0xf, 0xf, true);  // quad_perm [3,2,1,0]
    x += __int_as_float(t);
    t = __builtin_amdgcn_mov_dpp(__float_as_int(x), 0xB1, 0xf, 0xf, true);  // quad_perm [1,0,3,2]
    x += __int_as_float(t);
    return x;   // all 8 lanes of the group hold the 8-sum
}

__global__ __launch_bounds__(512) void snn_all(
    const float* __restrict__ x,
    const float* __restrict__ w1, const float* __restrict__ b1,
    const float* __restrict__ w2, const float* __restrict__ b2,
    const float* __restrict__ wf1, const float* __restrict__ bf1,
    const float* __restrict__ wf2, const float* __restrict__ bf2,
    float* __restrict__ out)
{
    __shared__ __align__(16) float swf1r[4 * 22 * 64 * 4];   // 22528 f = 90112 B, reordered wf1
    __shared__ __align__(16) float sx[2][LIN + 2];
    __shared__ float spool[2][16 * SP];
    __shared__ __align__(16) float sspk2[2][704];
    __shared__ float sspk3[2][32];

    const int tid = threadIdx.x;
    const int h   = tid >> 8;          // which sample of this block
    const int t2  = tid & 255;         // thread id within the sample
    const int b   = blockIdx.x * 2 + h;

    float* sxh    = sx[h];
    float* spoolh = spool[h];
    float* sspk2h = sspk2[h];
    float* sspk3h = sspk3[h];

    // ---------------- one-time init ----------------
    // reorder wf1 into LDS: dst[w4][i][l][c] = wf1[w4*8 + (l>>3)][ (l&7)*88 + i*4 + c ]
    for (int d = tid; d < 5632; d += 512) {          // float4 index
        int w4 = d / 1408;
        int r  = d - w4 * 1408;
        int i  = r >> 6;
        int l  = r & 63;
        int j  = w4 * 8 + (l >> 3);
        int sub = l & 7;
        float4 v = *reinterpret_cast<const float4*>(&wf1[(j * 176 + sub * 22 + i) * 4]);
        *reinterpret_cast<float4*>(&swf1r[d * 4]) = v;
    }
    for (int i = tid; i < 2 * 16 * SP; i += 512) ((float*)spool)[i] = 0.f;

    // ---- phase A setup: conv1. thread = (ca = t2&15, pg = t2>>4) ----
    const int ca = t2 & 15;
    const int pg = t2 >> 4;
    const float wA0 = w1[ca*13+0], wA1 = w1[ca*13+1], wA2 = w1[ca*13+2], wA3 = w1[ca*13+3],
                wA4 = w1[ca*13+4], wA5 = w1[ca*13+5], wA6 = w1[ca*13+6], wA7 = w1[ca*13+7],
                wA8 = w1[ca*13+8], wA9 = w1[ca*13+9], wA10 = w1[ca*13+10], wA11 = w1[ca*13+11],
                wA12 = w1[ca*13+12];
    const float bA = b1[ca];
    float m1a[5], m1b[5];
    #pragma unroll
    for (int j = 0; j < 5; ++j) { m1a[j] = 0.f; m1b[j] = 0.f; }

    // ---- phase B setup: conv2. lane = (cbl = lane>>3, ip = lane&7) ----
    const int lane = t2 & 63;
    const int w4id = t2 >> 6;          // wave within the half
    const int ip   = lane & 7;         // input row-pair index
    const int cbl  = lane >> 3;
    const int cb   = w4id * 8 + cbl;   // output channel
    const int wbase = cb * 112 + (2 * ip) * 7;
    const float wB00 = w2[wbase+0], wB01 = w2[wbase+1], wB02 = w2[wbase+2], wB03 = w2[wbase+3],
                wB04 = w2[wbase+4], wB05 = w2[wbase+5], wB06 = w2[wbase+6];
    const float wB10 = w2[wbase+7], wB11 = w2[wbase+8], wB12 = w2[wbase+9], wB13 = w2[wbase+10],
                wB14 = w2[wbase+11], wB15 = w2[wbase+12], wB16 = w2[wbase+13];
    const float bB = b2[cb];
    float m2_[3] = {0.f, 0.f, 0.f};    // membranes for outputs ip, ip+8, ip+16

    // ---- phase C setup: fc1 ----
    const float bC = bf1[t2 >> 3];
    float m3 = 0.f;

    // ---- phase D setup: fc2 ----
    float wD = 0.f, bD = 0.f;
    if (t2 < 64) {
        wD = wf2[(t2 >> 5) * 32 + (t2 & 31)];
        if ((t2 & 31) == 0) bD = bf2[t2 >> 5];
    }
    float m4 = 0.f, cnt = 0.f;

    // ---- initial x load ----
    const float* xb = x + (size_t)b * NT * LIN;
    if (t2 == 0) { sxh[0] = 0.f; sxh[LIN + 1] = 0.f; }
    sxh[1 + t2]       = xb[t2];
    sxh[1 + t2 + 256] = xb[t2 + 256];
    if (t2 < LIN - 512) sxh[1 + t2 + 512] = xb[t2 + 512];
    __syncthreads();

// ============ phase A macro: conv1 (k13,s5,p1) + LIF1 + maxpool2, literal j ============
#define A_J(j) { \
    const int p_ = ((j) == 4) ? (64 + pg) : (pg + 16 * (j)); \
    if ((j) < 4 || pg < 4) { \
        const float* xp_ = sxh + 10 * p_; \
        float2 q0_ = *(const float2*)(xp_ + 0); \
        float2 q1_ = *(const float2*)(xp_ + 2); \
        float2 q2_ = *(const float2*)(xp_ + 4); \
        float2 q3_ = *(const float2*)(xp_ + 6); \
        float2 q4_ = *(const float2*)(xp_ + 8); \
        float2 q5_ = *(const float2*)(xp_ + 10); \
        float2 q6_ = *(const float2*)(xp_ + 12); \
        float2 q7_ = *(const float2*)(xp_ + 14); \
        float2 q8_ = *(const float2*)(xp_ + 16); \
        float a0_ = wA0*q0_.x + wA1*q0_.y + wA2*q1_.x + wA3*q1_.y + wA4*q2_.x \
                  + wA5*q2_.y + wA6*q3_.x + wA7*q3_.y + wA8*q4_.x + wA9*q4_.y \
                  + wA10*q5_.x + wA11*q5_.y + wA12*q6_.x; \
        float a1_ = wA0*q2_.y + wA1*q3_.x + wA2*q3_.y + wA3*q4_.x + wA4*q4_.y \
                  + wA5*q5_.x + wA6*q5_.y + wA7*q6_.x + wA8*q6_.y + wA9*q7_.x \
                  + wA10*q7_.y + wA11*q8_.x + wA12*q8_.y; \
        float m0_ = m1a[(j)], mm_ = m1b[(j)]; \
        float r0_ = (m0_ > 1.f) ? 1.f : 0.f; \
        float r1_ = (mm_ > 1.f) ? 1.f : 0.f; \
        m0_ = 0.9f * m0_ + (a0_ + bA) - r0_; \
        mm_ = 0.9f * mm_ + (a1_ + bA) - r1_; \
        m1a[(j)] = m0_; m1b[(j)] = mm_; \
        spoolh[ca * SP + 1 + p_] = (m0_ > 1.f || mm_ > 1.f) ? 1.f : 0.f; \
    } }

// ============ phase B macros ============
#define PACKR(r) { \
    float v0_ = spoolh[(r) * SP + lane]; \
    float v1_ = spoolh[(r) * SP + 64 + (lane & 7)]; \
    unsigned long long lo_ = __ballot(v0_ > 0.5f); \
    uint32_t hi_ = (uint32_t)__ballot(v1_ > 0.5f) & 0xffu; \
    uint32_t l0_ = (uint32_t)lo_, l1_ = (uint32_t)(lo_ >> 32); \
    bool own_ = (ip == ((r) >> 1)); \
    if (((r) & 1) == 0) { b0 = own_ ? l0_ : b0; b1 = own_ ? l1_ : b1; b2 = own_ ? hi_ : b2; } \
    else                { c0 = own_ ? l0_ : c0; c1 = own_ ? l1_ : c1; c2 = own_ ? hi_ : c2; } }

#define XB(bp) ((float)((((bp) < 32 ? b0 : ((bp) < 64 ? b1 : b2)) >> ((bp) & 31)) & 1u))
#define XC(bp) ((float)((((bp) < 32 ? c0 : ((bp) < 64 ? c1 : c2)) >> ((bp) & 31)) & 1u))
#define FB(o,k) fb[(3 * (o) + (k)) % 7]
#define FC(o,k) fc[(3 * (o) + (k)) % 7]

#define C2_OUT(o) { \
    float s0_ = wB00*FB(o,0) + wB01*FB(o,1) + wB02*FB(o,2) + wB03*FB(o,3) \
              + wB04*FB(o,4) + wB05*FB(o,5) + wB06*FB(o,6); \
    float s1_ = wB10*FC(o,0) + wB11*FC(o,1) + wB12*FC(o,2) + wB13*FC(o,3) \
              + wB14*FC(o,4) + wB15*FC(o,5) + wB16*FC(o,6); \
    float s_ = dpp_add8(s0_ + s1_); \
    { const int j2_ = (o) >> 3; \
      bool own_ = (ip == ((o) & 7)); \
      float mm_ = m2_[j2_]; \
      float rr_ = (mm_ > 1.f) ? 1.f : 0.f; \
      float mn_ = 0.9f * mm_ + (s_ + bB) - rr_; \
      if (own_) { m2_[j2_] = mn_; spk_[j2_] = (mn_ > 1.f) ? 1.f : 0.f; } } \
    if ((o) < 21) { \
        FB(o,7) = XB(3*(o)+7); FB(o,8) = XB(3*(o)+8); FB(o,9) = XB(3*(o)+9); \
        FC(o,7) = XC(3*(o)+7); FC(o,8) = XC(3*(o)+8); FC(o,9) = XC(3*(o)+9); } }

    for (int t = 0; t < NT; ++t) {
        // ===== phase A =====
        A_J(0) A_J(1) A_J(2) A_J(3) A_J(4)
        __syncthreads();   // bar1: spool ready; sx free to overwrite

        // ===== prefetch x(t+1) =====
        float xp0 = 0.f, xp1 = 0.f, xp2 = 0.f;
        if (t + 1 < NT) {
            const float* xt = xb + (size_t)(t + 1) * LIN;
            xp0 = xt[t2];
            xp1 = xt[t2 + 256];
            if (t2 < LIN - 512) xp2 = xt[t2 + 512];
        }

        // ===== phase B: pack + conv2 + LIF2 =====
        uint32_t b0 = 0, b1 = 0, b2 = 0, c0 = 0, c1 = 0, c2 = 0;
        PACKR(0)  PACKR(1)  PACKR(2)  PACKR(3)
        PACKR(4)  PACKR(5)  PACKR(6)  PACKR(7)
        PACKR(8)  PACKR(9)  PACKR(10) PACKR(11)
        PACKR(12) PACKR(13) PACKR(14) PACKR(15)

        float fb[7], fc[7];
        fb[0]=XB(0); fb[1]=XB(1); fb[2]=XB(2); fb[3]=XB(3); fb[4]=XB(4); fb[5]=XB(5); fb[6]=XB(6);
        fc[0]=XC(0); fc[1]=XC(1); fc[2]=XC(2); fc[3]=XC(3); fc[4]=XC(4); fc[5]=XC(5); fc[6]=XC(6);
        float spk_[3] = {0.f, 0.f, 0.f};

        C2_OUT(0)  C2_OUT(1)  C2_OUT(2)  C2_OUT(3)  C2_OUT(4)  C2_OUT(5)
        C2_OUT(6)  C2_OUT(7)  C2_OUT(8)  C2_OUT(9)  C2_OUT(10) C2_OUT(11)
        C2_OUT(12) C2_OUT(13) C2_OUT(14) C2_OUT(15) C2_OUT(16) C2_OUT(17)
        C2_OUT(18) C2_OUT(19) C2_OUT(20) C2_OUT(21)

        sspk2h[cb * 22 + ip]     = spk_[0];
        sspk2h[cb * 22 + 8 + ip] = spk_[1];
        if (ip < 6) sspk2h[cb * 22 + 16 + ip] = spk_[2];

        // write x(t+1) (readers of sx are behind bar2+bar3)
        if (t + 1 < NT) {
            sxh[1 + t2]       = xp0;
            sxh[1 + t2 + 256] = xp1;
            if (t2 < LIN - 512) sxh[1 + t2 + 512] = xp2;
        }
        __syncthreads();   // bar2: sspk2 ready

        // ===== phase C: fc1 (704->32) + LIF3 =====
        {
            const float4* wr = reinterpret_cast<const float4*>(swf1r) + (w4id * 22) * 64 + lane;
            const float4* sp = reinterpret_cast<const float4*>(&sspk2h[(t2 & 7) * 88]);
            float a0 = 0.f, a1 = 0.f, a2 = 0.f, a3 = 0.f;
            #pragma unroll
            for (int i = 0; i < 22; ++i) {
                float4 w = wr[i * 64];
                float4 s = sp[i];
                a0 += w.x * s.x; a1 += w.y * s.y; a2 += w.z * s.z; a3 += w.w * s.w;
            }
            float acc = (a0 + a1) + (a2 + a3);
            acc = dpp_add8(acc);                    // sum over sub = t2&7
            float rr = (m3 > 1.f) ? 1.f : 0.f;
            m3 = 0.9f * m3 + (acc + bC) - rr;       // replicated across the 8 group lanes
            if ((t2 & 7) == 0) sspk3h[t2 >> 3] = (m3 > 1.f) ? 1.f : 0.f;
        }
        __syncthreads();   // bar3: sspk3 ready

        // ===== phase D: fc2 (32->2) + LIF4 + count =====
        if (t2 < 64) {
            float v = sspk3h[t2 & 31] * wD;
            v += __shfl_xor(v, 16, 32);
            v += __shfl_xor(v, 8, 32);
            v += __shfl_xor(v, 4, 32);
            v += __shfl_xor(v, 2, 32);
            v += __shfl_xor(v, 1, 32);
            if ((t2 & 31) == 0) {
                float rr = (m4 > 1.f) ? 1.f : 0.f;
                m4 = 0.9f * m4 + (v + bD) - rr;
                if (m4 > 1.f) cnt += 1.f;
            }
        }
        // no barrier: next writer of sspk3 (phase C of t+1) is behind bar1+bar2
    }

    if (t2 == 0)  out[b * 2 + 0] = cnt;
    if (t2 == 32) out[b * 2 + 1] = cnt;
}

extern "C" void kernel_launch(void* const* d_in, const int* in_sizes, int n_in,
                              void* d_out, int out_size, void* d_ws, size_t ws_size,
                              hipStream_t stream) {
    const float* x   = (const float*)d_in[0];
    const float* w1  = (const float*)d_in[1];
    const float* b1  = (const float*)d_in[2];
    const float* w2  = (const float*)d_in[3];
    const float* b2  = (const float*)d_in[4];
    const float* wf1 = (const float*)d_in[5];
    const float* bf1 = (const float*)d_in[6];
    const float* wf2 = (const float*)d_in[7];
    const float* bf2 = (const float*)d_in[8];
    float* out = (float*)d_out;

    snn_all<<<NB / 2, 512, 0, stream>>>(x, w1, b1, w2, b2, wf1, bf1, wf2, bf2, out);
}